// Round 8
// baseline (126.885 us; speedup 1.0000x reference)
//
#include <hip/hip_runtime.h>

// Single-kernel MFMA-tail, take 5 = round-6 body + round-7 compose-merge.
// Round-7 post-mortem: 32x32 path kept TWO f32x16 accumulators (32 VGPR) live
// + grid-stride loop state + prefetch -> live set blew the (256,6) 84-VGPR cap
// -> ~97 MB scratch traffic (FETCH 53/WRITE 78 MB), 59us. Fix: keep the merged
// compose (correctness-proven in r7) but revert the tail to round-6's
// 16x16x32 path (sequential f32x4 accumulators, proven to fit at 82.9us) and
// drop grid-stride/prefetch (one chunk per block, grid=4096). Saves the
// serialized compose dispatch (~3-5us) without round-7's spill.

using f16x8 = __attribute__((ext_vector_type(8))) _Float16;
using f32x4 = __attribute__((ext_vector_type(4))) float;

struct C { float r, i; };

__device__ __forceinline__ C cmul(C a, C b) {
    C o;
    o.r = fmaf(a.r, b.r, -(a.i * b.i));
    o.i = fmaf(a.r, b.i,   a.i * b.r);
    return o;
}

// o = u*a + w*b where u=(ur,ui), w=(wr,wi) are gate entries.
__device__ __forceinline__ C cmadd(float ur, float ui, float wr, float wi, C a, C b) {
    C o;
    o.r = fmaf(ur, a.r, fmaf(-ui, a.i, fmaf(wr, b.r, -(wi * b.i))));
    o.i = fmaf(ur, a.i, fmaf( ui, a.r, fmaf(wr, b.i,   wi * b.r)));
    return o;
}

template <int BP>
__device__ __forceinline__ void apply_gate(C st[16], float4 A4, float4 B4) {
#pragma unroll
    for (int i = 0; i < 8; i++) {
        const int lo = ((i >> BP) << (BP + 1)) | (i & ((1 << BP) - 1));
        const int hi = lo | (1 << BP);
        const C a = st[lo], b = st[hi];
        st[lo] = cmadd(A4.x, A4.y, A4.z, A4.w, a, b);
        st[hi] = cmadd(B4.x, B4.y, B4.z, B4.w, a, b);
    }
}

template <int CB, int TB>
__device__ __forceinline__ void cnot(C st[16]) {
#pragma unroll
    for (int i = 0; i < 16; i++) {
        if ((i & (1 << CB)) && !(i & (1 << TB))) {
            C t = st[i];
            st[i] = st[i | (1 << TB)];
            st[i | (1 << TB)] = t;
        }
    }
}

struct Enc { float r0, i0, r1, i1; };
// v_q = (cos(xn) e^{-i xn/2}, sin(xn) e^{+i xn/2}), xn = pi*tanh(x).
// HW v_sin/v_cos take REVOLUTIONS: sin(pi t/2) = v_sin(t/4), t in (-1,1).
__device__ __forceinline__ Enc encode(float xq) {
    const float ax = fabsf(xq);
    const float e  = __builtin_amdgcn_exp2f(ax * -2.8853900817779268f);  // exp(-2|x|)
    const float r  = __builtin_amdgcn_rcpf(1.0f + e);
    const float t  = copysignf((1.0f - e) * r, xq);                       // tanh(x)
    const float sh = __builtin_amdgcn_sinf(t * 0.25f);                    // sin(pi t/2)
    const float ch = __builtin_amdgcn_cosf(t * 0.25f);                    // cos(pi t/2)
    const float s  = 2.0f * sh * ch;                                      // sin(pi t)
    const float c  = fmaf(-2.0f * sh, sh, 1.0f);                          // cos(pi t)
    return {c * ch, -(c * sh), s * ch, s * sh};
}

// Wave-level LDS fence: compiler memory clobber stops reordering (the round-4
// bug); lgkmcnt(0) drains the DS queue; sched_barrier pins the point (rule #18).
__device__ __forceinline__ void wave_lds_fence() {
    asm volatile("s_waitcnt lgkmcnt(0)" ::: "memory");
    __builtin_amdgcn_sched_barrier(0);
}

#define ROWB 80   // LDS sample-row stride: 64 B data + 16 pad

__global__ __launch_bounds__(256, 6) void qlayer_kernel(const float* __restrict__ x,
                                                        const float* __restrict__ qw,
                                                        float* __restrict__ out, int B) {
    __shared__ float4 Ug[12][2];
    __shared__ __align__(16) unsigned char Wh_lds[2048];   // f16 W hi  [32][32]
    __shared__ __align__(16) unsigned char Wl_lds[2048];   // f16 W lo  (x2048)
    __shared__ __align__(16) unsigned char slab_all[4 * 64 * ROWB];  // per-wave S

    const int tid  = threadIdx.x;
    const int lane = tid & 63;
    const int wid  = tid >> 6;

    // ---- per-block compose (wave 0; correctness proven in round 7) -------
    if (tid < 12) {
        const float phi = qw[tid * 3 + 0];
        const float th  = qw[tid * 3 + 1];
        const float om  = qw[tid * 3 + 2];
        // Rot = RZ(om) RY(th) RZ(phi)
        float s, c;   __sincosf(0.5f * th, &s, &c);
        float sa, ca; __sincosf(0.5f * (phi + om), &sa, &ca);
        float sb, cb; __sincosf(0.5f * (phi - om), &sb, &cb);
        Ug[tid][0] = make_float4(c * ca, -c * sa, -s * cb, -s * sb);
        Ug[tid][1] = make_float4(s * cb, -s * sb, c * ca, c * sa);
    }
    if (tid < 16) {
        wave_lds_fence();   // Ug written by lanes 0-11, read by lanes 0-15 (wave 0)
        // Push basis state e_tid through the tail: ring0, L1, ring, L2, ring.
        C st[16];
#pragma unroll
        for (int i = 0; i < 16; i++) { st[i].r = 0.0f; st[i].i = 0.0f; }
        st[tid].r = 1.0f;

        cnot<3, 2>(st); cnot<2, 1>(st); cnot<1, 0>(st); cnot<0, 3>(st);
        apply_gate<3>(st, Ug[4][0], Ug[4][1]);
        apply_gate<2>(st, Ug[5][0], Ug[5][1]);
        apply_gate<1>(st, Ug[6][0], Ug[6][1]);
        apply_gate<0>(st, Ug[7][0], Ug[7][1]);
        cnot<3, 2>(st); cnot<2, 1>(st); cnot<1, 0>(st); cnot<0, 3>(st);
        apply_gate<3>(st, Ug[8][0], Ug[8][1]);
        apply_gate<2>(st, Ug[9][0], Ug[9][1]);
        apply_gate<1>(st, Ug[10][0], Ug[10][1]);
        apply_gate<0>(st, Ug[11][0], Ug[11][1]);
        cnot<3, 2>(st); cnot<2, 1>(st); cnot<1, 0>(st); cnot<0, 3>(st);

        // W real rep: out[j] = sum_k W[j][k] in[k], j/k = 2*dim + (0:re,1:im).
        // Basis t -> columns (2t, 2t+1): row 2d: (Tr, -Ti)  row 2d+1: (Ti, Tr)
        unsigned* whiW = reinterpret_cast<unsigned*>(Wh_lds);
        unsigned* wloW = reinterpret_cast<unsigned*>(Wl_lds);
#pragma unroll
        for (int d = 0; d < 16; d++) {
            const float vr = st[d].r, vi = st[d].i;
            const _Float16 hr  = (_Float16)vr, hi_ = (_Float16)vi;
            const _Float16 lr  = (_Float16)((vr - (float)hr)  * 2048.0f);
            const _Float16 li  = (_Float16)((vi - (float)hi_) * 2048.0f);
            const unsigned uhr = (unsigned)__builtin_bit_cast(unsigned short, hr);
            const unsigned uhi = (unsigned)__builtin_bit_cast(unsigned short, hi_);
            const unsigned ulr = (unsigned)__builtin_bit_cast(unsigned short, lr);
            const unsigned uli = (unsigned)__builtin_bit_cast(unsigned short, li);
            whiW[(2 * d) * 16 + tid]     = uhr | ((uhi ^ 0x8000u) << 16);
            whiW[(2 * d + 1) * 16 + tid] = uhi | (uhr << 16);
            wloW[(2 * d) * 16 + tid]     = ulr | ((uli ^ 0x8000u) << 16);
            wloW[(2 * d + 1) * 16 + tid] = uli | (ulr << 16);
        }
    }
    __syncthreads();

    // ---- W fragments (round-6 16x16 addressing, from LDS) ----------------
    // A-operand (W): row j = (lane&15) [+16 for 2nd M-tile], k-chunk 8*(lane>>4).
    const int jrow = lane & 15;
    const int kb   = (lane >> 4) * 16;  // byte offset of k-chunk in a 64 B row
    const f16x8 Wh0 = *reinterpret_cast<const f16x8*>(Wh_lds + jrow * 64 + kb);
    const f16x8 Wh1 = *reinterpret_cast<const f16x8*>(Wh_lds + (jrow + 16) * 64 + kb);
    const f16x8 Wl0 = *reinterpret_cast<const f16x8*>(Wl_lds + jrow * 64 + kb);
    const f16x8 Wl1 = *reinterpret_cast<const f16x8*>(Wl_lds + (jrow + 16) * 64 + kb);

    char* slab  = reinterpret_cast<char*>(slab_all) + wid * (64 * ROWB);
    char* myrow = slab + lane * ROWB;

    const int b  = blockIdx.x * 256 + tid;
    const int bl = (b < B) ? b : (B - 1);   // clamp: OOB lanes still join MFMA/shuffles
    const float4 xv = reinterpret_cast<const float4*>(x)[bl];
    const float xs[4] = {xv.x, xv.y, xv.z, xv.w};

    // Front end: encode + merge layer-0 Rot (product state).
    C v[4][2];
#pragma unroll
    for (int q = 0; q < 4; q++) {
        const Enc e = encode(xs[q]);
        const C a{e.r0, e.i0}, bv{e.r1, e.i1};
        const float4 A4 = Ug[q][0], B4 = Ug[q][1];
        v[q][0] = cmadd(A4.x, A4.y, A4.z, A4.w, a, bv);
        v[q][1] = cmadd(B4.x, B4.y, B4.z, B4.w, a, bv);
    }

    // Outer product fused with hi-f16 pack.
    C t01[4], t23[4];
#pragma unroll
    for (int i = 0; i < 4; i++) {
        t01[i] = cmul(v[0][(i >> 1) & 1], v[1][i & 1]);
        t23[i] = cmul(v[2][(i >> 1) & 1], v[3][i & 1]);
    }
    f16x8 vh[4];
#pragma unroll
    for (int i = 0; i < 16; i++) {
        const C s = cmul(t01[i >> 2], t23[i & 3]);
        vh[i >> 2][2 * (i & 3)]     = (_Float16)s.r;
        vh[i >> 2][2 * (i & 3) + 1] = (_Float16)s.i;
    }
#pragma unroll
    for (int c = 0; c < 4; c++)
        *reinterpret_cast<f16x8*>(myrow + c * 16) = vh[c];

    // CROSS-LANE handoff (within this wave only).
    wave_lds_fence();

    const int g = lane >> 4;
    const float f1 = (g & 1) ? 1.0f : 0.0f;   // d&2 mask
    const float f2 = (g & 2) ? 1.0f : 0.0f;   // d&4 mask
    const f32x4 Z = {0.f, 0.f, 0.f, 0.f};
    float e0 = 0.f, e1 = 0.f, e2 = 0.f, e3 = 0.f;

    // Tail: D = W * S^T (16x16x32). D col = sample = lane&15, row = j.
    // Lane holds j = 4g..4g+3 (c0) and 16+4g..+3 (c1) of sample 16n+(lane&15):
    // complex dims d = 2g, 2g+1 (c0) and 8+2g, 8+2g+1 (c1).
#pragma unroll
    for (int n = 0; n < 4; n++) {
        const f16x8 S = *reinterpret_cast<const f16x8*>(slab + (16 * n + jrow) * ROWB + kb);
        f32x4 m0 = __builtin_amdgcn_mfma_f32_16x16x32_f16(Wh0, S, Z, 0, 0, 0);
        f32x4 l0 = __builtin_amdgcn_mfma_f32_16x16x32_f16(Wl0, S, Z, 0, 0, 0);
        f32x4 m1 = __builtin_amdgcn_mfma_f32_16x16x32_f16(Wh1, S, Z, 0, 0, 0);
        f32x4 l1 = __builtin_amdgcn_mfma_f32_16x16x32_f16(Wl1, S, Z, 0, 0, 0);

        float c0[4], c1[4];
#pragma unroll
        for (int r = 0; r < 4; r++) {
            c0[r] = fmaf(l0[r], 4.8828125e-4f, m0[r]);   // + lo/2048
            c1[r] = fmaf(l1[r], 4.8828125e-4f, m1[r]);
        }
        const float p0 = fmaf(c0[1], c0[1], c0[0] * c0[0]);   // d = 2g
        const float p1 = fmaf(c0[3], c0[3], c0[2] * c0[2]);   // d = 2g+1
        const float p2 = fmaf(c1[1], c1[1], c1[0] * c1[0]);   // d = 8+2g
        const float p3 = fmaf(c1[3], c1[3], c1[2] * c1[2]);   // d = 8+2g+1
        const float Phi  = p2 + p3;
        const float Podd = p1 + p3;
        const float Pall = Phi + p0 + p1;
        float s3 = Phi, s2 = Pall * f2, s1 = Pall * f1, s0 = Podd;
        s3 += __shfl_xor(s3, 16); s2 += __shfl_xor(s2, 16);
        s1 += __shfl_xor(s1, 16); s0 += __shfl_xor(s0, 16);
        s3 += __shfl_xor(s3, 32); s2 += __shfl_xor(s2, 32);
        s1 += __shfl_xor(s1, 32); s0 += __shfl_xor(s0, 32);
        if (g == n) { e3 = s3; e2 = s2; e1 = s1; e0 = s0; }
    }

    if (b < B) {
        float4 ev;
        ev.x = fmaf(-2.0f, e3, 1.0f);
        ev.y = fmaf(-2.0f, e2, 1.0f);
        ev.z = fmaf(-2.0f, e1, 1.0f);
        ev.w = fmaf(-2.0f, e0, 1.0f);
        reinterpret_cast<float4*>(out)[b] = ev;
    }
}

extern "C" void kernel_launch(void* const* d_in, const int* in_sizes, int n_in,
                              void* d_out, int out_size, void* d_ws, size_t ws_size,
                              hipStream_t stream) {
    const float* x  = (const float*)d_in[0];
    const float* qw = (const float*)d_in[1];
    float* out = (float*)d_out;
    const int B = in_sizes[0] / 4;
    const int blocks = (B + 255) / 256;   // one 256-sample chunk per block
    qlayer_kernel<<<blocks, 256, 0, stream>>>(x, qw, out, B);
}

// Round 9
// 85.052 us; speedup vs baseline: 1.4919x; 1.4919x over previous
//
#include <hip/hip_runtime.h>

// Two-kernel MFMA-tail, take 6 = round-6 structure + round-7's 32x32 tail.
// Round-7/8 post-mortem: merging compose into the main kernel is twice-refuted
// (spill signature: excess HBM WRITE at VGPR cap + per-block serial compose
// behind a barrier). Round-6 two-kernel structure (82.9us) is the proven base.
// The 32x32 readout algebra PASSED correctness in round 7 (failed only on
// register economics under grid-stride+prefetch): 8 MFMAs (was 16), half the
// post-MFMA VALU (2-way not 4-way tile waste), 8 shfl (was 32). In the simple
// one-chunk-per-block structure the tail live set is ~74 VGPR < 84 cap.
// Split-f16 W retained -> arithmetic identical to round 6 (absmax 0.00390625).

using f16x8  = __attribute__((ext_vector_type(8))) _Float16;
using f32x16 = __attribute__((ext_vector_type(16))) float;

struct C { float r, i; };

__device__ __forceinline__ C cmul(C a, C b) {
    C o;
    o.r = fmaf(a.r, b.r, -(a.i * b.i));
    o.i = fmaf(a.r, b.i,   a.i * b.r);
    return o;
}

// o = u*a + w*b where u=(ur,ui), w=(wr,wi) are gate entries.
__device__ __forceinline__ C cmadd(float ur, float ui, float wr, float wi, C a, C b) {
    C o;
    o.r = fmaf(ur, a.r, fmaf(-ui, a.i, fmaf(wr, b.r, -(wi * b.i))));
    o.i = fmaf(ur, a.i, fmaf( ui, a.r, fmaf(wr, b.i,   wi * b.r)));
    return o;
}

template <int BP>
__device__ __forceinline__ void apply_gate(C st[16], float4 A4, float4 B4) {
#pragma unroll
    for (int i = 0; i < 8; i++) {
        const int lo = ((i >> BP) << (BP + 1)) | (i & ((1 << BP) - 1));
        const int hi = lo | (1 << BP);
        const C a = st[lo], b = st[hi];
        st[lo] = cmadd(A4.x, A4.y, A4.z, A4.w, a, b);
        st[hi] = cmadd(B4.x, B4.y, B4.z, B4.w, a, b);
    }
}

template <int CB, int TB>
__device__ __forceinline__ void cnot(C st[16]) {
#pragma unroll
    for (int i = 0; i < 16; i++) {
        if ((i & (1 << CB)) && !(i & (1 << TB))) {
            C t = st[i];
            st[i] = st[i | (1 << TB)];
            st[i | (1 << TB)] = t;
        }
    }
}

struct Enc { float r0, i0, r1, i1; };
// v_q = (cos(xn) e^{-i xn/2}, sin(xn) e^{+i xn/2}), xn = pi*tanh(x).
// HW v_sin/v_cos take REVOLUTIONS: sin(pi t/2) = v_sin(t/4), t in (-1,1).
__device__ __forceinline__ Enc encode(float xq) {
    const float ax = fabsf(xq);
    const float e  = __builtin_amdgcn_exp2f(ax * -2.8853900817779268f);  // exp(-2|x|)
    const float r  = __builtin_amdgcn_rcpf(1.0f + e);
    const float t  = copysignf((1.0f - e) * r, xq);                       // tanh(x)
    const float sh = __builtin_amdgcn_sinf(t * 0.25f);                    // sin(pi t/2)
    const float ch = __builtin_amdgcn_cosf(t * 0.25f);                    // cos(pi t/2)
    const float s  = 2.0f * sh * ch;                                      // sin(pi t)
    const float c  = fmaf(-2.0f * sh, sh, 1.0f);                          // cos(pi t)
    return {c * ch, -(c * sh), s * ch, s * sh};
}

// Wave-level LDS fence: compiler memory clobber stops reordering (the round-4
// bug); lgkmcnt(0) drains the DS queue; sched_barrier pins the point (rule #18).
__device__ __forceinline__ void wave_lds_fence() {
    asm volatile("s_waitcnt lgkmcnt(0)" ::: "memory");
    __builtin_amdgcn_sched_barrier(0);
}

// Workspace layout (bytes): [0,2048) Whi f16[32][32]; [2048,4096) Wlo (x2048);
// [4096,4224) layer-0 gates: float4[4][2].
#define WS_WLO 2048
#define WS_UG0 4096
#define ROWB 80   // LDS sample-row stride: 64 B data + 16 pad

// ---------------- Kernel 1: compose tail matrix W (1 block, 64 threads) ------
__global__ void qcompose_kernel(const float* __restrict__ qw, float* __restrict__ ws) {
    __shared__ float4 Ug[12][2];
    const int tid = threadIdx.x;
    if (tid < 12) {
        const float phi = qw[tid * 3 + 0];
        const float th  = qw[tid * 3 + 1];
        const float om  = qw[tid * 3 + 2];
        // Rot = RZ(om) RY(th) RZ(phi)
        float s, c;   __sincosf(0.5f * th, &s, &c);
        float sa, ca; __sincosf(0.5f * (phi + om), &sa, &ca);
        float sb, cb; __sincosf(0.5f * (phi - om), &sb, &cb);
        Ug[tid][0] = make_float4(c * ca, -c * sa, -s * cb, -s * sb);
        Ug[tid][1] = make_float4(s * cb, -s * sb, c * ca, c * sa);
    }
    __syncthreads();

    if (tid < 4) {  // export layer-0 gates for the main kernel
        float4* o = reinterpret_cast<float4*>(reinterpret_cast<char*>(ws) + WS_UG0);
        o[2 * tid]     = Ug[tid][0];
        o[2 * tid + 1] = Ug[tid][1];
    }

    if (tid < 16) {
        // Push basis state e_tid through the tail: ring0, L1, ring, L2, ring.
        C st[16];
#pragma unroll
        for (int i = 0; i < 16; i++) { st[i].r = 0.0f; st[i].i = 0.0f; }
        st[tid].r = 1.0f;

        cnot<3, 2>(st); cnot<2, 1>(st); cnot<1, 0>(st); cnot<0, 3>(st);
        apply_gate<3>(st, Ug[4][0], Ug[4][1]);
        apply_gate<2>(st, Ug[5][0], Ug[5][1]);
        apply_gate<1>(st, Ug[6][0], Ug[6][1]);
        apply_gate<0>(st, Ug[7][0], Ug[7][1]);
        cnot<3, 2>(st); cnot<2, 1>(st); cnot<1, 0>(st); cnot<0, 3>(st);
        apply_gate<3>(st, Ug[8][0], Ug[8][1]);
        apply_gate<2>(st, Ug[9][0], Ug[9][1]);
        apply_gate<1>(st, Ug[10][0], Ug[10][1]);
        apply_gate<0>(st, Ug[11][0], Ug[11][1]);
        cnot<3, 2>(st); cnot<2, 1>(st); cnot<1, 0>(st); cnot<0, 3>(st);

        // W real rep: out[j] = sum_k W[j][k] in[k], j/k = 2*dim + (0:re,1:im).
        // Basis t -> columns (2t, 2t+1): row 2d: (Tr, -Ti)  row 2d+1: (Ti, Tr)
        _Float16* whi = reinterpret_cast<_Float16*>(ws);
        _Float16* wlo = reinterpret_cast<_Float16*>(reinterpret_cast<char*>(ws) + WS_WLO);
        const int k0 = 2 * tid, k1 = k0 + 1;
#pragma unroll
        for (int d = 0; d < 16; d++) {
            const int j0 = 2 * d, j1 = j0 + 1;
            const float vr = st[d].r, vi = st[d].i;
            float v[4]  = {vr, vi, -vi, vr};
            int   jj[4] = {j0, j1, j0, j1};
            int   kk[4] = {k0, k0, k1, k1};
#pragma unroll
            for (int e = 0; e < 4; e++) {
                _Float16 h = (_Float16)v[e];
                _Float16 l = (_Float16)((v[e] - (float)h) * 2048.0f);  // lo pre-scaled
                whi[jj[e] * 32 + kk[e]] = h;
                wlo[jj[e] * 32 + kk[e]] = l;
            }
        }
    }
}

// ---------------- Kernel 2: main, 32x32 MFMA tail, wave-local ----------------
__global__ __launch_bounds__(256, 6) void qlayer_kernel(const float* __restrict__ x,
                                                        const float* __restrict__ ws,
                                                        float* __restrict__ out, int B) {
    __shared__ __align__(16) unsigned char slab_all[4 * 64 * ROWB];   // 20 KiB/WG
    const int tid  = threadIdx.x;
    const int lane = tid & 63;
    const int wid  = tid >> 6;
    char* slab  = reinterpret_cast<char*>(slab_all) + wid * (64 * ROWB);
    char* myrow = slab + lane * ROWB;

    const char* wsb = reinterpret_cast<const char*>(ws);

    // W fragments = MFMA A-operand (32x32): lane holds row j=lane&31,
    // k-chunk 8*(lane>>5) of each 16-k step (round-7-verified addressing).
    const int j32 = lane & 31;
    const int h   = lane >> 5;
    const f16x8 Wh0 = *reinterpret_cast<const f16x8*>(wsb + j32 * 64 + h * 16);
    const f16x8 Wh1 = *reinterpret_cast<const f16x8*>(wsb + j32 * 64 + 32 + h * 16);
    const f16x8 Wl0 = *reinterpret_cast<const f16x8*>(wsb + WS_WLO + j32 * 64 + h * 16);
    const f16x8 Wl1 = *reinterpret_cast<const f16x8*>(wsb + WS_WLO + j32 * 64 + 32 + h * 16);
    const float4* ug0 = reinterpret_cast<const float4*>(wsb + WS_UG0);

    const int b  = blockIdx.x * 256 + tid;
    const int bl = (b < B) ? b : (B - 1);   // clamp: OOB lanes still join MFMA/shuffles
    const float4 xv = reinterpret_cast<const float4*>(x)[bl];
    const float xs[4] = {xv.x, xv.y, xv.z, xv.w};

    // Front end: encode + merge layer-0 Rot (product state).
    C v[4][2];
#pragma unroll
    for (int q = 0; q < 4; q++) {
        const Enc e = encode(xs[q]);
        const C a{e.r0, e.i0}, bv{e.r1, e.i1};
        const float4 A4 = ug0[2 * q], B4 = ug0[2 * q + 1];
        v[q][0] = cmadd(A4.x, A4.y, A4.z, A4.w, a, bv);
        v[q][1] = cmadd(B4.x, B4.y, B4.z, B4.w, a, bv);
    }

    // Outer product fused with hi-f16 pack.
    C t01[4], t23[4];
#pragma unroll
    for (int i = 0; i < 4; i++) {
        t01[i] = cmul(v[0][(i >> 1) & 1], v[1][i & 1]);
        t23[i] = cmul(v[2][(i >> 1) & 1], v[3][i & 1]);
    }
    f16x8 vh[4];
#pragma unroll
    for (int i = 0; i < 16; i++) {
        const C s = cmul(t01[i >> 2], t23[i & 3]);
        vh[i >> 2][2 * (i & 3)]     = (_Float16)s.r;
        vh[i >> 2][2 * (i & 3) + 1] = (_Float16)s.i;
    }
#pragma unroll
    for (int c = 0; c < 4; c++)
        *reinterpret_cast<f16x8*>(myrow + c * 16) = vh[c];

    // CROSS-LANE handoff (within this wave only).
    wave_lds_fence();

    // Tail: D = W * S^T, 32x32x16, 2 chained k-steps, 2 sample-tiles of 32.
    // D layout (round-7-verified): col = sample = lane&31,
    // row = (reg&3)+8*(reg>>2)+4h; pairs (2m,2m+1) = (re,im) of
    // d(m) = 4*(m>>1) + 2h + (m&1). Own tile = h.
    float r3[2], r2[2], r1[2], r0[2];
#pragma unroll
    for (int n = 0; n < 2; n++) {
        const char* srow = slab + (32 * n + j32) * ROWB + h * 16;
        const f16x8 S0 = *reinterpret_cast<const f16x8*>(srow);
        const f16x8 S1 = *reinterpret_cast<const f16x8*>(srow + 32);
        const f32x16 Z = {0.f,0.f,0.f,0.f,0.f,0.f,0.f,0.f,
                          0.f,0.f,0.f,0.f,0.f,0.f,0.f,0.f};
        f32x16 D = __builtin_amdgcn_mfma_f32_32x32x16_f16(Wh0, S0, Z, 0, 0, 0);
        D        = __builtin_amdgcn_mfma_f32_32x32x16_f16(Wh1, S1, D, 0, 0, 0);
        f32x16 L = __builtin_amdgcn_mfma_f32_32x32x16_f16(Wl0, S0, Z, 0, 0, 0);
        L        = __builtin_amdgcn_mfma_f32_32x32x16_f16(Wl1, S1, L, 0, 0, 0);

        float p[8];
#pragma unroll
        for (int m = 0; m < 8; m++) {
            const float c0 = fmaf(L[2 * m],     4.8828125e-4f, D[2 * m]);
            const float c1 = fmaf(L[2 * m + 1], 4.8828125e-4f, D[2 * m + 1]);
            p[m] = fmaf(c1, c1, c0 * c0);
        }
        const float e67 = p[6] + p[7];
        float t3 = (p[4] + p[5]) + e67;                    // d&8: m=4..7
        float t2 = (p[2] + p[3]) + e67;                    // d&4: m=2,3,6,7
        float t0 = (p[1] + p[3]) + (p[5] + p[7]);          // d&1: m odd
        const float tAll = ((p[0] + p[2]) + (p[4] + p[6])) + t0;
        float t1 = h ? tAll : 0.0f;                        // d&2 <=> h
        t3 += __shfl_xor(t3, 32); t2 += __shfl_xor(t2, 32);
        t1 += __shfl_xor(t1, 32); t0 += __shfl_xor(t0, 32);
        r3[n] = t3; r2[n] = t2; r1[n] = t1; r0[n] = t0;
    }
    const float e3 = h ? r3[1] : r3[0];
    const float e2 = h ? r2[1] : r2[0];
    const float e1 = h ? r1[1] : r1[0];
    const float e0 = h ? r0[1] : r0[0];

    if (b < B) {
        float4 ev;
        ev.x = fmaf(-2.0f, e3, 1.0f);
        ev.y = fmaf(-2.0f, e2, 1.0f);
        ev.z = fmaf(-2.0f, e1, 1.0f);
        ev.w = fmaf(-2.0f, e0, 1.0f);
        reinterpret_cast<float4*>(out)[b] = ev;
    }
}

extern "C" void kernel_launch(void* const* d_in, const int* in_sizes, int n_in,
                              void* d_out, int out_size, void* d_ws, size_t ws_size,
                              hipStream_t stream) {
    const float* x  = (const float*)d_in[0];
    const float* qw = (const float*)d_in[1];
    float* out = (float*)d_out;
    float* ws  = (float*)d_ws;
    const int B = in_sizes[0] / 4;
    const int blocks = (B + 255) / 256;   // one 256-sample chunk per block
    qcompose_kernel<<<1, 64, 0, stream>>>(qw, ws);
    qlayer_kernel<<<blocks, 256, 0, stream>>>(x, ws, out, B);
}

// Round 10
// 79.968 us; speedup vs baseline: 1.5867x; 1.0636x over previous
//
#include <hip/hip_runtime.h>

// Two-kernel MFMA-tail, take 7 = round-9 structure, hi-only-f16 W, (256,8).
// Round-9 post-mortem: 32x32 tail correct; bench flat vs round 6 (83-85us,
// within noise) because the kernel (~20us) sits under a ~60us harness floor.
// This round removes the split-f16 Wlo correction path: W is unitary-bounded
// so hi-only f16 W adds <=~6e-3 EV error (threshold 0.0198, current 0.0039).
// Payoff: 4 of 8 MFMAs, 16 fmas, 2 global loads gone, and ~24 VGPRs freed
// (Wlo frags + L accumulator) -> live set ~55 fits a 64-reg cap ->
// __launch_bounds__(256,8) = 8 waves/SIMD (+33% latency hiding; 8 WGs x
// 20KiB = exactly 160KiB LDS/CU). The config rounds 1/7/8 spilled at is now
// reachable because the tail halved. Fallbacks: absmax>0.0198 -> restore Wlo;
// spill (WRITE_SIZE balloon) -> revert (256,6).

using f16x8  = __attribute__((ext_vector_type(8))) _Float16;
using f32x16 = __attribute__((ext_vector_type(16))) float;

struct C { float r, i; };

__device__ __forceinline__ C cmul(C a, C b) {
    C o;
    o.r = fmaf(a.r, b.r, -(a.i * b.i));
    o.i = fmaf(a.r, b.i,   a.i * b.r);
    return o;
}

// o = u*a + w*b where u=(ur,ui), w=(wr,wi) are gate entries.
__device__ __forceinline__ C cmadd(float ur, float ui, float wr, float wi, C a, C b) {
    C o;
    o.r = fmaf(ur, a.r, fmaf(-ui, a.i, fmaf(wr, b.r, -(wi * b.i))));
    o.i = fmaf(ur, a.i, fmaf( ui, a.r, fmaf(wr, b.i,   wi * b.r)));
    return o;
}

template <int BP>
__device__ __forceinline__ void apply_gate(C st[16], float4 A4, float4 B4) {
#pragma unroll
    for (int i = 0; i < 8; i++) {
        const int lo = ((i >> BP) << (BP + 1)) | (i & ((1 << BP) - 1));
        const int hi = lo | (1 << BP);
        const C a = st[lo], b = st[hi];
        st[lo] = cmadd(A4.x, A4.y, A4.z, A4.w, a, b);
        st[hi] = cmadd(B4.x, B4.y, B4.z, B4.w, a, b);
    }
}

template <int CB, int TB>
__device__ __forceinline__ void cnot(C st[16]) {
#pragma unroll
    for (int i = 0; i < 16; i++) {
        if ((i & (1 << CB)) && !(i & (1 << TB))) {
            C t = st[i];
            st[i] = st[i | (1 << TB)];
            st[i | (1 << TB)] = t;
        }
    }
}

struct Enc { float r0, i0, r1, i1; };
// v_q = (cos(xn) e^{-i xn/2}, sin(xn) e^{+i xn/2}), xn = pi*tanh(x).
// HW v_sin/v_cos take REVOLUTIONS: sin(pi t/2) = v_sin(t/4), t in (-1,1).
__device__ __forceinline__ Enc encode(float xq) {
    const float ax = fabsf(xq);
    const float e  = __builtin_amdgcn_exp2f(ax * -2.8853900817779268f);  // exp(-2|x|)
    const float r  = __builtin_amdgcn_rcpf(1.0f + e);
    const float t  = copysignf((1.0f - e) * r, xq);                       // tanh(x)
    const float sh = __builtin_amdgcn_sinf(t * 0.25f);                    // sin(pi t/2)
    const float ch = __builtin_amdgcn_cosf(t * 0.25f);                    // cos(pi t/2)
    const float s  = 2.0f * sh * ch;                                      // sin(pi t)
    const float c  = fmaf(-2.0f * sh, sh, 1.0f);                          // cos(pi t)
    return {c * ch, -(c * sh), s * ch, s * sh};
}

// Wave-level LDS fence: compiler memory clobber stops reordering (the round-4
// bug); lgkmcnt(0) drains the DS queue; sched_barrier pins the point (rule #18).
__device__ __forceinline__ void wave_lds_fence() {
    asm volatile("s_waitcnt lgkmcnt(0)" ::: "memory");
    __builtin_amdgcn_sched_barrier(0);
}

// Workspace layout (bytes): [0,2048) Whi f16[32][32];
// [4096,4224) layer-0 gates: float4[4][2].  (Wlo slot retired.)
#define WS_UG0 4096
#define ROWB 80   // LDS sample-row stride: 64 B data + 16 pad

// ---------------- Kernel 1: compose tail matrix W (1 block, 64 threads) ------
__global__ void qcompose_kernel(const float* __restrict__ qw, float* __restrict__ ws) {
    __shared__ float4 Ug[12][2];
    const int tid = threadIdx.x;
    if (tid < 12) {
        const float phi = qw[tid * 3 + 0];
        const float th  = qw[tid * 3 + 1];
        const float om  = qw[tid * 3 + 2];
        // Rot = RZ(om) RY(th) RZ(phi)
        float s, c;   __sincosf(0.5f * th, &s, &c);
        float sa, ca; __sincosf(0.5f * (phi + om), &sa, &ca);
        float sb, cb; __sincosf(0.5f * (phi - om), &sb, &cb);
        Ug[tid][0] = make_float4(c * ca, -c * sa, -s * cb, -s * sb);
        Ug[tid][1] = make_float4(s * cb, -s * sb, c * ca, c * sa);
    }
    __syncthreads();

    if (tid < 4) {  // export layer-0 gates for the main kernel
        float4* o = reinterpret_cast<float4*>(reinterpret_cast<char*>(ws) + WS_UG0);
        o[2 * tid]     = Ug[tid][0];
        o[2 * tid + 1] = Ug[tid][1];
    }

    if (tid < 16) {
        // Push basis state e_tid through the tail: ring0, L1, ring, L2, ring.
        C st[16];
#pragma unroll
        for (int i = 0; i < 16; i++) { st[i].r = 0.0f; st[i].i = 0.0f; }
        st[tid].r = 1.0f;

        cnot<3, 2>(st); cnot<2, 1>(st); cnot<1, 0>(st); cnot<0, 3>(st);
        apply_gate<3>(st, Ug[4][0], Ug[4][1]);
        apply_gate<2>(st, Ug[5][0], Ug[5][1]);
        apply_gate<1>(st, Ug[6][0], Ug[6][1]);
        apply_gate<0>(st, Ug[7][0], Ug[7][1]);
        cnot<3, 2>(st); cnot<2, 1>(st); cnot<1, 0>(st); cnot<0, 3>(st);
        apply_gate<3>(st, Ug[8][0], Ug[8][1]);
        apply_gate<2>(st, Ug[9][0], Ug[9][1]);
        apply_gate<1>(st, Ug[10][0], Ug[10][1]);
        apply_gate<0>(st, Ug[11][0], Ug[11][1]);
        cnot<3, 2>(st); cnot<2, 1>(st); cnot<1, 0>(st); cnot<0, 3>(st);

        // W real rep: out[j] = sum_k W[j][k] in[k], j/k = 2*dim + (0:re,1:im).
        // Basis t -> columns (2t, 2t+1): row 2d: (Tr, -Ti)  row 2d+1: (Ti, Tr)
        _Float16* whi = reinterpret_cast<_Float16*>(ws);
        const int k0 = 2 * tid, k1 = k0 + 1;
#pragma unroll
        for (int d = 0; d < 16; d++) {
            const int j0 = 2 * d, j1 = j0 + 1;
            const float vr = st[d].r, vi = st[d].i;
            whi[j0 * 32 + k0] = (_Float16)vr;
            whi[j1 * 32 + k0] = (_Float16)vi;
            whi[j0 * 32 + k1] = (_Float16)(-vi);
            whi[j1 * 32 + k1] = (_Float16)vr;
        }
    }
}

// ---------------- Kernel 2: main, 32x32 MFMA tail, hi-only W -----------------
__global__ __launch_bounds__(256, 8) void qlayer_kernel(const float* __restrict__ x,
                                                        const float* __restrict__ ws,
                                                        float* __restrict__ out, int B) {
    __shared__ __align__(16) unsigned char slab_all[4 * 64 * ROWB];   // 20 KiB/WG
    const int tid  = threadIdx.x;
    const int lane = tid & 63;
    const int wid  = tid >> 6;
    char* slab  = reinterpret_cast<char*>(slab_all) + wid * (64 * ROWB);
    char* myrow = slab + lane * ROWB;

    const char* wsb = reinterpret_cast<const char*>(ws);

    // W fragments = MFMA A-operand (32x32): lane holds row j=lane&31,
    // k-chunk 8*(lane>>5) of each 16-k step (round-7/9-verified addressing).
    const int j32 = lane & 31;
    const int h   = lane >> 5;
    const f16x8 Wh0 = *reinterpret_cast<const f16x8*>(wsb + j32 * 64 + h * 16);
    const f16x8 Wh1 = *reinterpret_cast<const f16x8*>(wsb + j32 * 64 + 32 + h * 16);
    const float4* ug0 = reinterpret_cast<const float4*>(wsb + WS_UG0);

    const int b  = blockIdx.x * 256 + tid;
    const int bl = (b < B) ? b : (B - 1);   // clamp: OOB lanes still join MFMA/shuffles
    const float4 xv = reinterpret_cast<const float4*>(x)[bl];
    const float xs[4] = {xv.x, xv.y, xv.z, xv.w};

    // Front end: encode + merge layer-0 Rot (product state).
    C v[4][2];
#pragma unroll
    for (int q = 0; q < 4; q++) {
        const Enc e = encode(xs[q]);
        const C a{e.r0, e.i0}, bv{e.r1, e.i1};
        const float4 A4 = ug0[2 * q], B4 = ug0[2 * q + 1];
        v[q][0] = cmadd(A4.x, A4.y, A4.z, A4.w, a, bv);
        v[q][1] = cmadd(B4.x, B4.y, B4.z, B4.w, a, bv);
    }

    // Outer product fused with hi-f16 pack.
    C t01[4], t23[4];
#pragma unroll
    for (int i = 0; i < 4; i++) {
        t01[i] = cmul(v[0][(i >> 1) & 1], v[1][i & 1]);
        t23[i] = cmul(v[2][(i >> 1) & 1], v[3][i & 1]);
    }
    f16x8 vh[4];
#pragma unroll
    for (int i = 0; i < 16; i++) {
        const C s = cmul(t01[i >> 2], t23[i & 3]);
        vh[i >> 2][2 * (i & 3)]     = (_Float16)s.r;
        vh[i >> 2][2 * (i & 3) + 1] = (_Float16)s.i;
    }
#pragma unroll
    for (int c = 0; c < 4; c++)
        *reinterpret_cast<f16x8*>(myrow + c * 16) = vh[c];

    // CROSS-LANE handoff (within this wave only).
    wave_lds_fence();

    // Tail: D = W * S^T, 32x32x16, 2 chained k-steps, 2 sample-tiles of 32.
    // D layout (round-7/9-verified): col = sample = lane&31,
    // row = (reg&3)+8*(reg>>2)+4h; pairs (2m,2m+1) = (re,im) of
    // d(m) = 4*(m>>1) + 2h + (m&1). Own tile = h.
    float r3[2], r2[2], r1[2], r0[2];
#pragma unroll
    for (int n = 0; n < 2; n++) {
        const char* srow = slab + (32 * n + j32) * ROWB + h * 16;
        const f16x8 S0 = *reinterpret_cast<const f16x8*>(srow);
        const f16x8 S1 = *reinterpret_cast<const f16x8*>(srow + 32);
        const f32x16 Z = {0.f,0.f,0.f,0.f,0.f,0.f,0.f,0.f,
                          0.f,0.f,0.f,0.f,0.f,0.f,0.f,0.f};
        f32x16 D = __builtin_amdgcn_mfma_f32_32x32x16_f16(Wh0, S0, Z, 0, 0, 0);
        D        = __builtin_amdgcn_mfma_f32_32x32x16_f16(Wh1, S1, D, 0, 0, 0);

        float p[8];
#pragma unroll
        for (int m = 0; m < 8; m++)
            p[m] = fmaf(D[2 * m + 1], D[2 * m + 1], D[2 * m] * D[2 * m]);

        const float e67 = p[6] + p[7];
        float t3 = (p[4] + p[5]) + e67;                    // d&8: m=4..7
        float t2 = (p[2] + p[3]) + e67;                    // d&4: m=2,3,6,7
        float t0 = (p[1] + p[3]) + (p[5] + p[7]);          // d&1: m odd
        const float tAll = ((p[0] + p[2]) + (p[4] + p[6])) + t0;
        float t1 = h ? tAll : 0.0f;                        // d&2 <=> h
        t3 += __shfl_xor(t3, 32); t2 += __shfl_xor(t2, 32);
        t1 += __shfl_xor(t1, 32); t0 += __shfl_xor(t0, 32);
        r3[n] = t3; r2[n] = t2; r1[n] = t1; r0[n] = t0;
    }
    const float e3 = h ? r3[1] : r3[0];
    const float e2 = h ? r2[1] : r2[0];
    const float e1 = h ? r1[1] : r1[0];
    const float e0 = h ? r0[1] : r0[0];

    if (b < B) {
        float4 ev;
        ev.x = fmaf(-2.0f, e3, 1.0f);
        ev.y = fmaf(-2.0f, e2, 1.0f);
        ev.z = fmaf(-2.0f, e1, 1.0f);
        ev.w = fmaf(-2.0f, e0, 1.0f);
        reinterpret_cast<float4*>(out)[b] = ev;
    }
}

extern "C" void kernel_launch(void* const* d_in, const int* in_sizes, int n_in,
                              void* d_out, int out_size, void* d_ws, size_t ws_size,
                              hipStream_t stream) {
    const float* x  = (const float*)d_in[0];
    const float* qw = (const float*)d_in[1];
    float* out = (float*)d_out;
    float* ws  = (float*)d_ws;
    const int B = in_sizes[0] / 4;
    const int blocks = (B + 255) / 256;   // one 256-sample chunk per block
    qcompose_kernel<<<1, 64, 0, stream>>>(qw, ws);
    qlayer_kernel<<<blocks, 256, 0, stream>>>(x, ws, out, B);
}